// Round 7
// baseline (3173.983 us; speedup 1.0000x reference)
//
#include <hip/hip_runtime.h>
#include <hip/hip_bf16.h>
#include <stdint.h>

// Problem constants (fixed by the reference)
#define TT 32768   // total tokens
#define DD 2048    // model dim
#define HH 5632    // hidden dim
#define NE 8       // experts

typedef __bf16 bf16;
typedef __bf16 bf16x8 __attribute__((ext_vector_type(8)));
typedef float  f32x4  __attribute__((ext_vector_type(4)));

__device__ __forceinline__ void gl16(const void* g, void* l) {
    __builtin_amdgcn_global_load_lds(
        (const __attribute__((address_space(1))) void*)g,
        (__attribute__((address_space(3))) void*)l, 16, 0, 0);
}
#define VMW(n) asm volatile("s_waitcnt vmcnt(" #n ")" ::: "memory")
#define LGKM0() do { asm volatile("s_waitcnt lgkmcnt(0)" ::: "memory"); \
                     __builtin_amdgcn_sched_barrier(0); } while (0)
#define BARRIER() __builtin_amdgcn_s_barrier()

// LDS XOR-swizzle for 64-B rows (BK=32 bf16): measured 0 bank conflicts (r2).
__device__ __forceinline__ int swz(int off) { return off ^ (((off >> 7) & 3) << 4); }

__device__ __forceinline__ int expert_of(const int* counts, int row0) {
    int base = 0;
    for (int i = 0; i < NE; ++i) { int c = counts[i]; if (row0 < base + c) return i; base += c; }
    return NE - 1;
}

// ---------------- f32 -> bf16 convert ----------------
__global__ __launch_bounds__(256)
void k_cvt(const float* __restrict__ in, bf16* __restrict__ out, long n) {
    long i = ((long)blockIdx.x * 256 + threadIdx.x) * 8;
    const long stride = (long)gridDim.x * 256 * 8;
    for (; i < n; i += stride) {
        const float4* p = (const float4*)(in + i);
        float4 a = p[0], b = p[1];
        union { bf16 v[8]; uint4 u; } r;
        r.v[0] = (bf16)a.x; r.v[1] = (bf16)a.y; r.v[2] = (bf16)a.z; r.v[3] = (bf16)a.w;
        r.v[4] = (bf16)b.x; r.v[5] = (bf16)b.y; r.v[6] = (bf16)b.z; r.v[7] = (bf16)b.w;
        *(uint4*)(out + i) = r.u;
    }
}

// =====================================================================
// Persistent fused GEMM1: grid=256 (1 block/CU), 22 segments/block,
// flattened K-loop: 5-deep LDS (160 KiB), stage lead 4, r5-verified
// vmcnt books run UNINTERRUPTED across segment boundaries (staging
// bases switch 4 tiles early at tc==60; epilogue after pair tc==62;
// tail drain once per kernel).
// =====================================================================
#define M1_LOAD(bufb, NA, NB1, NB3) do {                                      \
    const char* nb_ = sm + (bufb);                                            \
    _Pragma("unroll")                                                         \
    for (int mi = 0; mi < 8; ++mi)                                            \
        NA[mi] = *(const bf16x8*)(nb_ + aoff0 + mi * 1024);                   \
    _Pragma("unroll")                                                         \
    for (int ni = 0; ni < 2; ++ni) {                                          \
        NB1[ni] = *(const bf16x8*)(nb_ + 16384 + boff0 + ni * 1024);          \
        NB3[ni] = *(const bf16x8*)(nb_ + 24576 + boff0 + ni * 1024);          \
    }                                                                         \
    __builtin_amdgcn_sched_barrier(0);                                        \
} while (0)

#define M1_ITER(g, bLb, bSb, ko, CA, CB1, CB3, NA, NB1, NB3) do {             \
    if ((g) + 4 < GTOT) { stage((ko), (bSb)); VMW(8); }                       \
    else if ((g) == GTOT - 4) { VMW(4); }                                     \
    else if ((g) == GTOT - 3) { VMW(0); }                                     \
    LGKM0();                                                                  \
    if ((g) + 1 < GTOT) M1_LOAD((bLb), NA, NB1, NB3);                         \
    __builtin_amdgcn_s_setprio(1);                                            \
    _Pragma("unroll")                                                         \
    for (int mi = 0; mi < 8; ++mi)                                            \
    _Pragma("unroll")                                                         \
    for (int ni = 0; ni < 2; ++ni) {                                          \
        acc1[mi][ni] = __builtin_amdgcn_mfma_f32_16x16x32_bf16(CA[mi], CB1[ni], acc1[mi][ni], 0, 0, 0); \
        acc3[mi][ni] = __builtin_amdgcn_mfma_f32_16x16x32_bf16(CA[mi], CB3[ni], acc3[mi][ni], 0, 0, 0); \
    }                                                                         \
    __builtin_amdgcn_s_setprio(0);                                            \
    BARRIER();                                                                \
} while (0)

__global__ __launch_bounds__(512, 2)
void k_moe1(const bf16* __restrict__ xb, const bf16* __restrict__ w1b,
            const bf16* __restrict__ w3b, const int* __restrict__ counts,
            bf16* __restrict__ h) {
    extern __shared__ __align__(16) char sm[];
    const int tid = threadIdx.x;
    const int c = blockIdx.x & 7;      // XCD (round-robin dispatch)
    const int j = blockIdx.x >> 3;     // [0,32) position within XCD
    const int NSEG = 22;               // items per block
    const int NT = 64;                 // K-tiles per segment (DD/32)
    const int GTOT = NSEG * NT;        // 1408

    // item map (r6-proven): local = seg*32 + j; nt = local>>4 (slow),
    // mt = 16c + local&15 -> concurrent blocks share 2 weight panels (L2).
    const int s0 = swz(tid * 16);      // swizzled 128-row staging offset
    const int s1 = 8192 + s0;          // rows 128..255 (swz(8192+x)=8192+swz(x))
    const int dst0 = tid * 16;

    const char *sa0, *sa1, *sa2, *sa3;
    int sseg = 0;                      // staging segment
    auto set_bases = [&](int sg) {
        int local = sg * 32 + j;
        int r0 = ((c << 4) + (local & 15)) * 256;
        int c0 = (local >> 4) * 128;
        int e = expert_of(counts, r0);   // loads retire here (addr dependency)
        sa0 = (const char*)xb + (((size_t)(r0 + (s0 >> 6)) * DD) << 1) + (s0 & 63);
        sa1 = (const char*)xb + (((size_t)(r0 + (s1 >> 6)) * DD) << 1) + (s1 & 63);
        const char* w1p = (const char*)(w1b + (size_t)e * HH * DD);
        const char* w3p = (const char*)(w3b + (size_t)e * HH * DD);
        sa2 = w1p + (((size_t)(c0 + (s0 >> 6)) * DD) << 1) + (s0 & 63);
        sa3 = w3p + (((size_t)(c0 + (s0 >> 6)) * DD) << 1) + (s0 & 63);
    };
    set_bases(0);

    auto stage = [&](int ko, int bufb) {
        char* db = sm + bufb;
        gl16(sa0 + ko, db + dst0);
        gl16(sa1 + ko, db + 8192 + dst0);
        gl16(sa2 + ko, db + 16384 + dst0);
        gl16(sa3 + ko, db + 24576 + dst0);
    };

    const int lane = tid & 63, wv = tid >> 6;
    const int wrow = wv >> 2, wcol = wv & 3;      // wave = 128 rows x 32 cols/mat
    const int lrow = lane & 15, kb = (lane >> 4) << 4;
    const int aoff0 = swz((wrow * 128 + lrow) * 64 + kb);   // + mi*1024
    const int boff0 = swz((wcol * 32 + lrow) * 64 + kb);    // + ni*1024

    f32x4 acc1[8][2] = {};
    f32x4 acc3[8][2] = {};
    bf16x8 Xa[8], Xb1[2], Xb3[2], Ya[8], Yb1[2], Yb3[2];

    // prologue: tiles 0..3 of seg 0 into buffers 0..3
    stage(0, 0); stage(64, 32768); stage(128, 65536); stage(192, 98304);
    VMW(8);            // tiles 0,1 landed
    BARRIER();
    M1_LOAD(0, Xa, Xb1, Xb3);

    int tc = 0;                 // pair-base t within compute segment
    int stk = 256;              // staging ko (bytes) for slot A
    int b0 = 0;                 // gp % 5
    int cseg = 0;
    int crow0 = ((c << 4) + (j & 15)) * 256;
    int ccol0 = (j >> 4) * 128;

    for (int gp = 0; gp < GTOT; gp += 2) {
        int bL1 = b0 + 1; if (bL1 >= 5) bL1 -= 5;   // load buf, slot A (tile gp+1)
        int bL2 = b0 + 2; if (bL2 >= 5) bL2 -= 5;   // load buf, slot B (tile gp+2)
        int bS1 = b0 + 4; if (bS1 >= 5) bS1 -= 5;   // stage buf, slot A (tile gp+4)
        const int bS2 = b0;                          // stage buf, slot B (tile gp+5)
        if (tc == 60 && sseg + 1 < NSEG) { ++sseg; set_bases(sseg); stk = 0; }

        M1_ITER(gp,     bL1 << 15, bS1 << 15, stk,      Xa, Xb1, Xb3, Ya, Yb1, Yb3);
        M1_ITER(gp + 1, bL2 << 15, bS2 << 15, stk + 64, Ya, Yb1, Yb3, Xa, Xb1, Xb3);
        stk += 128;
        b0 += 2; if (b0 >= 5) b0 -= 5;

        if (tc == 62) {
            // segment epilogue: bf16-round h1,h3, silu in f32, bf16 h
#pragma unroll
            for (int mi = 0; mi < 8; ++mi)
#pragma unroll
                for (int ni = 0; ni < 2; ++ni) {
#pragma unroll
                    for (int jj = 0; jj < 4; ++jj) {
                        int row = crow0 + wrow * 128 + mi * 16 + ((lane >> 4) << 2) + jj;
                        int col = ccol0 + wcol * 32 + ni * 16 + lrow;
                        float f1 = (float)(bf16)acc1[mi][ni][jj];
                        float f3 = (float)(bf16)acc3[mi][ni][jj];
                        float s = f1 / (1.0f + __expf(-f1));
                        h[(size_t)row * HH + col] = (bf16)(s * f3);
                    }
                    acc1[mi][ni] = (f32x4){0.f, 0.f, 0.f, 0.f};
                    acc3[mi][ni] = (f32x4){0.f, 0.f, 0.f, 0.f};
                }
            ++cseg;
            int local = cseg * 32 + j;
            crow0 = ((c << 4) + (local & 15)) * 256;
            ccol0 = (local >> 4) * 128;
            tc = 0;
        } else {
            tc += 2;
        }
    }
}

// =====================================================================
// Persistent GEMM2: out = bf16(h @ W2^T) -> f32.  BM=BN=256, BK=32.
// grid=256, 4 segments/block, same flattened books. nt-slow item map.
// =====================================================================
#define G2_LOAD(bufb, NA, NB) do {                                            \
    const char* nb_ = sm + (bufb);                                            \
    _Pragma("unroll")                                                         \
    for (int mi = 0; mi < 8; ++mi)                                            \
        NA[mi] = *(const bf16x8*)(nb_ + aoff0 + mi * 1024);                   \
    _Pragma("unroll")                                                         \
    for (int ni = 0; ni < 4; ++ni)                                            \
        NB[ni] = *(const bf16x8*)(nb_ + 16384 + boff0 + ni * 1024);           \
    __builtin_amdgcn_sched_barrier(0);                                        \
} while (0)

#define G2_ITER(g, bLb, bSb, ko, CA, CB, NA, NB) do {                         \
    if ((g) + 4 < GTOT) { stage((ko), (bSb)); VMW(8); }                       \
    else if ((g) == GTOT - 4) { VMW(4); }                                     \
    else if ((g) == GTOT - 3) { VMW(0); }                                     \
    LGKM0();                                                                  \
    if ((g) + 1 < GTOT) G2_LOAD((bLb), NA, NB);                               \
    __builtin_amdgcn_s_setprio(1);                                            \
    _Pragma("unroll")                                                         \
    for (int mi = 0; mi < 8; ++mi)                                            \
    _Pragma("unroll")                                                         \
    for (int ni = 0; ni < 4; ++ni)                                            \
        acc[mi][ni] = __builtin_amdgcn_mfma_f32_16x16x32_bf16(CA[mi], CB[ni], acc[mi][ni], 0, 0, 0); \
    __builtin_amdgcn_s_setprio(0);                                            \
    BARRIER();                                                                \
} while (0)

__global__ __launch_bounds__(512, 2)
void k_g2(const bf16* __restrict__ hb, const bf16* __restrict__ w2b,
          const int* __restrict__ counts, float* __restrict__ out) {
    extern __shared__ __align__(16) char sm[];
    const int tid = threadIdx.x;
    const int c = blockIdx.x & 7;
    const int j = blockIdx.x >> 3;
    const int NSEG = 4;
    const int NT = 176;                // HH/32
    const int GTOT = NSEG * NT;        // 704

    const int s0 = swz(tid * 16);
    const int s1 = 8192 + s0;
    const int dst0 = tid * 16;

    const char *sa0, *sa1, *sa2, *sa3;
    int sseg = 0;
    auto set_bases = [&](int sg) {
        int local = sg * 32 + j;                  // [0,128)
        int r0 = ((c << 4) + (local & 15)) * 256;
        int c0 = (local >> 4) * 256;              // nt slow: 2 shared W2 panels
        int e = expert_of(counts, r0);
        sa0 = (const char*)hb + (((size_t)(r0 + (s0 >> 6)) * HH) << 1) + (s0 & 63);
        sa1 = (const char*)hb + (((size_t)(r0 + (s1 >> 6)) * HH) << 1) + (s1 & 63);
        const char* wp = (const char*)(w2b + (size_t)e * DD * HH);
        sa2 = wp + (((size_t)(c0 + (s0 >> 6)) * HH) << 1) + (s0 & 63);
        sa3 = wp + (((size_t)(c0 + (s1 >> 6)) * HH) << 1) + (s1 & 63);
    };
    set_bases(0);

    auto stage = [&](int ko, int bufb) {
        char* db = sm + bufb;
        gl16(sa0 + ko, db + dst0);
        gl16(sa1 + ko, db + 8192 + dst0);
        gl16(sa2 + ko, db + 16384 + dst0);
        gl16(sa3 + ko, db + 24576 + dst0);
    };

    const int lane = tid & 63, wv = tid >> 6;
    const int wrow = wv >> 2, wcol = wv & 3;      // wave = 128 x 64
    const int lrow = lane & 15, kb = (lane >> 4) << 4;
    const int aoff0 = swz((wrow * 128 + lrow) * 64 + kb);
    const int boff0 = swz((wcol * 64 + lrow) * 64 + kb);

    f32x4 acc[8][4] = {};
    bf16x8 Xa[8], Xb[4], Ya[8], Yb[4];

    stage(0, 0); stage(64, 32768); stage(128, 65536); stage(192, 98304);
    VMW(8);
    BARRIER();
    G2_LOAD(0, Xa, Xb);

    int tc = 0, stk = 256, b0 = 0;
    int cseg = 0;
    int crow0 = ((c << 4) + (j & 15)) * 256;
    int ccol0 = (j >> 4) * 256;

    for (int gp = 0; gp < GTOT; gp += 2) {
        int bL1 = b0 + 1; if (bL1 >= 5) bL1 -= 5;
        int bL2 = b0 + 2; if (bL2 >= 5) bL2 -= 5;
        int bS1 = b0 + 4; if (bS1 >= 5) bS1 -= 5;
        const int bS2 = b0;
        if (tc == 172 && sseg + 1 < NSEG) { ++sseg; set_bases(sseg); stk = 0; }

        G2_ITER(gp,     bL1 << 15, bS1 << 15, stk,      Xa, Xb, Ya, Yb);
        G2_ITER(gp + 1, bL2 << 15, bS2 << 15, stk + 64, Ya, Yb, Xa, Xb);
        stk += 128;
        b0 += 2; if (b0 >= 5) b0 -= 5;

        if (tc == 174) {
#pragma unroll
            for (int mi = 0; mi < 8; ++mi)
#pragma unroll
                for (int ni = 0; ni < 4; ++ni) {
#pragma unroll
                    for (int jj = 0; jj < 4; ++jj) {
                        int row = crow0 + wrow * 128 + mi * 16 + ((lane >> 4) << 2) + jj;
                        int col = ccol0 + wcol * 64 + ni * 16 + lrow;
                        out[(size_t)row * DD + col] = (float)(bf16)acc[mi][ni][jj];
                    }
                    acc[mi][ni] = (f32x4){0.f, 0.f, 0.f, 0.f};
                }
            ++cseg;
            int local = cseg * 32 + j;
            crow0 = ((c << 4) + (local & 15)) * 256;
            ccol0 = (local >> 4) * 256;
            tc = 0;
        } else {
            tc += 2;
        }
    }
}

extern "C" void kernel_launch(void* const* d_in, const int* in_sizes, int n_in,
                              void* d_out, int out_size, void* d_ws, size_t ws_size,
                              hipStream_t stream) {
    const float* x      = (const float*)d_in[0];
    const float* w1     = (const float*)d_in[1];
    const float* w2     = (const float*)d_in[2];
    const float* w3     = (const float*)d_in[3];
    const int*   counts = (const int*)d_in[4];
    float* out = (float*)d_out;

    const size_t xb_b = (size_t)TT * DD * 2;        // 128 MiB
    const size_t h_b  = (size_t)TT * HH * 2;        // 352 MiB
    const size_t w_b  = (size_t)NE * HH * DD * 2;   // 176 MiB each
    const size_t need_full = xb_b + h_b + 2 * w_b;  // 832 MiB (proven available r2-r6)
    if (ws_size < need_full) return;

    bf16* xb  = (bf16*)d_ws;
    bf16* h   = (bf16*)((char*)d_ws + xb_b);
    bf16* wsA = (bf16*)((char*)d_ws + xb_b + h_b);
    bf16* wsB = (bf16*)((char*)d_ws + xb_b + h_b + w_b);

    hipFuncSetAttribute((const void*)k_moe1, hipFuncAttributeMaxDynamicSharedMemorySize, 163840);
    hipFuncSetAttribute((const void*)k_g2,   hipFuncAttributeMaxDynamicSharedMemorySize, 163840);

    k_cvt<<<2048, 256, 0, stream>>>(x,  xb,  (long)TT * DD);
    k_cvt<<<2048, 256, 0, stream>>>(w1, wsA, (long)NE * HH * DD);
    k_cvt<<<2048, 256, 0, stream>>>(w3, wsB, (long)NE * HH * DD);
    k_moe1<<<256, 512, 163840, stream>>>(xb, wsA, wsB, counts, h);
    k_cvt<<<2048, 256, 0, stream>>>(w2, wsA, (long)NE * DD * HH);   // reuse slot A
    k_g2<<<256, 512, 163840, stream>>>(h, wsA, counts, out);
}

// Round 8
// 2648.266 us; speedup vs baseline: 1.1985x; 1.1985x over previous
//
#include <hip/hip_runtime.h>
#include <hip/hip_bf16.h>
#include <stdint.h>

// Problem constants (fixed by the reference)
#define TT 32768   // total tokens
#define DD 2048    // model dim
#define HH 5632    // hidden dim
#define NE 8       // experts

typedef __bf16 bf16;
typedef __bf16 bf16x8 __attribute__((ext_vector_type(8)));
typedef float  f32x4  __attribute__((ext_vector_type(4)));

__device__ __forceinline__ void gl16(const void* g, void* l) {
    __builtin_amdgcn_global_load_lds(
        (const __attribute__((address_space(1))) void*)g,
        (__attribute__((address_space(3))) void*)l, 16, 0, 0);
}
#define VMW(n) asm volatile("s_waitcnt vmcnt(" #n ")" ::: "memory")
#define LGKM0() do { asm volatile("s_waitcnt lgkmcnt(0)" ::: "memory"); \
                     __builtin_amdgcn_sched_barrier(0); } while (0)
#define BARRIER() __builtin_amdgcn_s_barrier()

// LDS XOR-swizzle for 64-B rows (BK=32 bf16): measured 0 bank conflicts (r2).
__device__ __forceinline__ int swz(int off) { return off ^ (((off >> 7) & 3) << 4); }

__device__ __forceinline__ int expert_of(const int* counts, int row0) {
    int base = 0;
    for (int i = 0; i < NE; ++i) { int c = counts[i]; if (row0 < base + c) return i; base += c; }
    return NE - 1;
}

// ---------------- f32 -> bf16 convert ----------------
__global__ __launch_bounds__(256)
void k_cvt(const float* __restrict__ in, bf16* __restrict__ out, long n) {
    long i = ((long)blockIdx.x * 256 + threadIdx.x) * 8;
    const long stride = (long)gridDim.x * 256 * 8;
    for (; i < n; i += stride) {
        const float4* p = (const float4*)(in + i);
        float4 a = p[0], b = p[1];
        union { bf16 v[8]; uint4 u; } r;
        r.v[0] = (bf16)a.x; r.v[1] = (bf16)a.y; r.v[2] = (bf16)a.z; r.v[3] = (bf16)a.w;
        r.v[4] = (bf16)b.x; r.v[5] = (bf16)b.y; r.v[6] = (bf16)b.z; r.v[7] = (bf16)b.w;
        *(uint4*)(out + i) = r.u;
    }
}

// =====================================================================
// Persistent fused GEMM1 (r7 measured winner, kept verbatim):
// grid=256, 22 segments/block, flattened K-loop, 5-deep LDS (160 KiB),
// stage lead 4, vmcnt books continuous across segment boundaries.
// =====================================================================
#define M1_LOAD(bufb, NA, NB1, NB3) do {                                      \
    const char* nb_ = sm + (bufb);                                            \
    _Pragma("unroll")                                                         \
    for (int mi = 0; mi < 8; ++mi)                                            \
        NA[mi] = *(const bf16x8*)(nb_ + aoff0 + mi * 1024);                   \
    _Pragma("unroll")                                                         \
    for (int ni = 0; ni < 2; ++ni) {                                          \
        NB1[ni] = *(const bf16x8*)(nb_ + 16384 + boff0 + ni * 1024);          \
        NB3[ni] = *(const bf16x8*)(nb_ + 24576 + boff0 + ni * 1024);          \
    }                                                                         \
    __builtin_amdgcn_sched_barrier(0);                                        \
} while (0)

#define M1_ITER(g, bLb, bSb, ko, CA, CB1, CB3, NA, NB1, NB3) do {             \
    if ((g) + 4 < GTOT) { stage((ko), (bSb)); VMW(8); }                       \
    else if ((g) == GTOT - 4) { VMW(4); }                                     \
    else if ((g) == GTOT - 3) { VMW(0); }                                     \
    LGKM0();                                                                  \
    if ((g) + 1 < GTOT) M1_LOAD((bLb), NA, NB1, NB3);                         \
    __builtin_amdgcn_s_setprio(1);                                            \
    _Pragma("unroll")                                                         \
    for (int mi = 0; mi < 8; ++mi)                                            \
    _Pragma("unroll")                                                         \
    for (int ni = 0; ni < 2; ++ni) {                                          \
        acc1[mi][ni] = __builtin_amdgcn_mfma_f32_16x16x32_bf16(CA[mi], CB1[ni], acc1[mi][ni], 0, 0, 0); \
        acc3[mi][ni] = __builtin_amdgcn_mfma_f32_16x16x32_bf16(CA[mi], CB3[ni], acc3[mi][ni], 0, 0, 0); \
    }                                                                         \
    __builtin_amdgcn_s_setprio(0);                                            \
    BARRIER();                                                                \
} while (0)

__global__ __launch_bounds__(512, 2)
void k_moe1(const bf16* __restrict__ xb, const bf16* __restrict__ w1b,
            const bf16* __restrict__ w3b, const int* __restrict__ counts,
            bf16* __restrict__ h) {
    extern __shared__ __align__(16) char sm[];
    const int tid = threadIdx.x;
    const int c = blockIdx.x & 7;      // XCD (round-robin dispatch)
    const int j = blockIdx.x >> 3;     // [0,32) position within XCD
    const int NSEG = 22;
    const int NT = 64;                 // DD/32
    const int GTOT = NSEG * NT;        // 1408

    const int s0 = swz(tid * 16);
    const int s1 = 8192 + s0;
    const int dst0 = tid * 16;

    const char *sa0, *sa1, *sa2, *sa3;
    int sseg = 0;
    auto set_bases = [&](int sg) {
        int local = sg * 32 + j;
        int r0 = ((c << 4) + (local & 15)) * 256;
        int c0 = (local >> 4) * 128;
        int e = expert_of(counts, r0);
        sa0 = (const char*)xb + (((size_t)(r0 + (s0 >> 6)) * DD) << 1) + (s0 & 63);
        sa1 = (const char*)xb + (((size_t)(r0 + (s1 >> 6)) * DD) << 1) + (s1 & 63);
        const char* w1p = (const char*)(w1b + (size_t)e * HH * DD);
        const char* w3p = (const char*)(w3b + (size_t)e * HH * DD);
        sa2 = w1p + (((size_t)(c0 + (s0 >> 6)) * DD) << 1) + (s0 & 63);
        sa3 = w3p + (((size_t)(c0 + (s0 >> 6)) * DD) << 1) + (s0 & 63);
    };
    set_bases(0);

    auto stage = [&](int ko, int bufb) {
        char* db = sm + bufb;
        gl16(sa0 + ko, db + dst0);
        gl16(sa1 + ko, db + 8192 + dst0);
        gl16(sa2 + ko, db + 16384 + dst0);
        gl16(sa3 + ko, db + 24576 + dst0);
    };

    const int lane = tid & 63, wv = tid >> 6;
    const int wrow = wv >> 2, wcol = wv & 3;
    const int lrow = lane & 15, kb = (lane >> 4) << 4;
    const int aoff0 = swz((wrow * 128 + lrow) * 64 + kb);
    const int boff0 = swz((wcol * 32 + lrow) * 64 + kb);

    f32x4 acc1[8][2] = {};
    f32x4 acc3[8][2] = {};
    bf16x8 Xa[8], Xb1[2], Xb3[2], Ya[8], Yb1[2], Yb3[2];

    stage(0, 0); stage(64, 32768); stage(128, 65536); stage(192, 98304);
    VMW(8);
    BARRIER();
    M1_LOAD(0, Xa, Xb1, Xb3);

    int tc = 0, stk = 256, b0 = 0;
    int cseg = 0;
    int crow0 = ((c << 4) + (j & 15)) * 256;
    int ccol0 = (j >> 4) * 128;

    for (int gp = 0; gp < GTOT; gp += 2) {
        int bL1 = b0 + 1; if (bL1 >= 5) bL1 -= 5;
        int bL2 = b0 + 2; if (bL2 >= 5) bL2 -= 5;
        int bS1 = b0 + 4; if (bS1 >= 5) bS1 -= 5;
        const int bS2 = b0;
        if (tc == 60 && sseg + 1 < NSEG) { ++sseg; set_bases(sseg); stk = 0; }

        M1_ITER(gp,     bL1 << 15, bS1 << 15, stk,      Xa, Xb1, Xb3, Ya, Yb1, Yb3);
        M1_ITER(gp + 1, bL2 << 15, bS2 << 15, stk + 64, Ya, Yb1, Yb3, Xa, Xb1, Xb3);
        stk += 128;
        b0 += 2; if (b0 >= 5) b0 -= 5;

        if (tc == 62) {
#pragma unroll
            for (int mi = 0; mi < 8; ++mi)
#pragma unroll
                for (int ni = 0; ni < 2; ++ni) {
#pragma unroll
                    for (int jj = 0; jj < 4; ++jj) {
                        int row = crow0 + wrow * 128 + mi * 16 + ((lane >> 4) << 2) + jj;
                        int col = ccol0 + wcol * 32 + ni * 16 + lrow;
                        float f1 = (float)(bf16)acc1[mi][ni][jj];
                        float f3 = (float)(bf16)acc3[mi][ni][jj];
                        float s = f1 / (1.0f + __expf(-f1));
                        h[(size_t)row * HH + col] = (bf16)(s * f3);
                    }
                    acc1[mi][ni] = (f32x4){0.f, 0.f, 0.f, 0.f};
                    acc3[mi][ni] = (f32x4){0.f, 0.f, 0.f, 0.f};
                }
            ++cseg;
            int local = cseg * 32 + j;
            crow0 = ((c << 4) + (local & 15)) * 256;
            ccol0 = (local >> 4) * 128;
            tc = 0;
        } else {
            tc += 2;
        }
    }
}

// =====================================================================
// GEMM2, restored r5/r6 non-persistent frag-pipelined kernel (measured
// 635 us) with ONE change: mt-fast item map within the XCD chunk so the
// 32 concurrent blocks/XCD share 2 W2 panels (5.8 MB, ~L2) instead of
// 8 panels (23 MB).  grid=1024, static NT=176 loop (compiler-unrolled).
// =====================================================================
#define G2_LOAD(t1, NA, NB) do {                                              \
    const char* nb_ = sm + (size_t)((t1) % 5) * 32768;                        \
    _Pragma("unroll")                                                         \
    for (int mi = 0; mi < 8; ++mi)                                            \
        NA[mi] = *(const bf16x8*)(nb_ + aoff0 + mi * 1024);                   \
    _Pragma("unroll")                                                         \
    for (int ni = 0; ni < 4; ++ni)                                            \
        NB[ni] = *(const bf16x8*)(nb_ + 16384 + boff0 + ni * 1024);           \
    __builtin_amdgcn_sched_barrier(0);                                        \
} while (0)

#define G2_ITER(t, CA, CB, NA, NB) do {                                       \
    if ((t) + 4 < NT) { stage((t) + 4); VMW(8); }                             \
    else if ((t) == NT - 4) { VMW(4); }                                       \
    else if ((t) == NT - 3) { VMW(0); }                                       \
    LGKM0();                                                                  \
    if ((t) + 1 < NT) G2_LOAD((t) + 1, NA, NB);                               \
    __builtin_amdgcn_s_setprio(1);                                            \
    _Pragma("unroll")                                                         \
    for (int mi = 0; mi < 8; ++mi)                                            \
    _Pragma("unroll")                                                         \
    for (int ni = 0; ni < 4; ++ni)                                            \
        acc[mi][ni] = __builtin_amdgcn_mfma_f32_16x16x32_bf16(CA[mi], CB[ni], acc[mi][ni], 0, 0, 0); \
    __builtin_amdgcn_s_setprio(0);                                            \
    BARRIER();                                                                \
} while (0)

__global__ __launch_bounds__(512, 2)
void k_g2(const bf16* __restrict__ hb, const bf16* __restrict__ w2b,
          const int* __restrict__ counts, float* __restrict__ out) {
    extern __shared__ __align__(16) char sm[];
    const int tid = threadIdx.x;
    // mt-fast map: XCD c (= blockIdx&7, round-robin dispatch; 1024%8==0 so
    // later generations keep the property) owns mt in [16c,16c+16) = expert c.
    const int c = blockIdx.x & 7;
    const int local = blockIdx.x >> 3;            // [0,128)
    const int nt = local >> 4;                    // slow (8 values)
    const int mt = (c << 4) + (local & 15);       // fast (16 per XCD)
    const int row0 = mt * 256, col0 = nt * 256;
    const int e = expert_of(counts, row0);

    const char *sa0, *sa1, *sa2, *sa3;
    {
        int off0 = tid * 16, off1 = 8192 + tid * 16;
        int s0 = swz(off0), s1 = swz(off1);
        sa0 = (const char*)hb + (((size_t)(row0 + (s0 >> 6)) * HH) << 1) + (s0 & 63);
        sa1 = (const char*)hb + (((size_t)(row0 + (s1 >> 6)) * HH) << 1) + (s1 & 63);
        const char* wp = (const char*)(w2b + (size_t)e * DD * HH);
        sa2 = wp + (((size_t)(col0 + (s0 >> 6)) * HH) << 1) + (s0 & 63);
        sa3 = wp + (((size_t)(col0 + (s1 >> 6)) * HH) << 1) + (s1 & 63);
    }
    const int dst0 = tid * 16;
    auto stage = [&](int kt) {
        char* db = sm + (size_t)(kt % 5) * 32768;
        const size_t ko = (size_t)kt << 6;
        gl16(sa0 + ko, db + dst0);
        gl16(sa1 + ko, db + 8192 + dst0);
        gl16(sa2 + ko, db + 16384 + dst0);
        gl16(sa3 + ko, db + 24576 + dst0);
    };

    const int lane = tid & 63, wv = tid >> 6;
    const int wrow = wv >> 2, wcol = wv & 3;      // wave = 128 x 64
    const int lrow = lane & 15, kb = (lane >> 4) << 4;

    const int aoff0 = swz((wrow * 128 + lrow) * 64 + kb);   // + mi*1024
    const int boff0 = swz((wcol * 64 + lrow) * 64 + kb);    // + ni*1024

    f32x4 acc[8][4] = {};
    bf16x8 Xa[8], Xb[4], Ya[8], Yb[4];

    const int NT = HH / 32;   // 176
    stage(0); stage(1); stage(2); stage(3);
    VMW(8);
    BARRIER();
    G2_LOAD(0, Xa, Xb);
    for (int t = 0; t < NT; t += 2) {
        G2_ITER(t,     Xa, Xb, Ya, Yb);
        G2_ITER(t + 1, Ya, Yb, Xa, Xb);
    }

#pragma unroll
    for (int mi = 0; mi < 8; ++mi)
#pragma unroll
        for (int ni = 0; ni < 4; ++ni)
#pragma unroll
            for (int j = 0; j < 4; ++j) {
                int row = row0 + wrow * 128 + mi * 16 + ((lane >> 4) << 2) + j;
                int col = col0 + wcol * 64 + ni * 16 + lrow;
                out[(size_t)row * DD + col] = (float)(bf16)acc[mi][ni][j];
            }
}

extern "C" void kernel_launch(void* const* d_in, const int* in_sizes, int n_in,
                              void* d_out, int out_size, void* d_ws, size_t ws_size,
                              hipStream_t stream) {
    const float* x      = (const float*)d_in[0];
    const float* w1     = (const float*)d_in[1];
    const float* w2     = (const float*)d_in[2];
    const float* w3     = (const float*)d_in[3];
    const int*   counts = (const int*)d_in[4];
    float* out = (float*)d_out;

    const size_t xb_b = (size_t)TT * DD * 2;        // 128 MiB
    const size_t h_b  = (size_t)TT * HH * 2;        // 352 MiB
    const size_t w_b  = (size_t)NE * HH * DD * 2;   // 176 MiB each
    const size_t need_full = xb_b + h_b + 2 * w_b;  // 832 MiB (proven available)
    if (ws_size < need_full) return;

    bf16* xb  = (bf16*)d_ws;
    bf16* h   = (bf16*)((char*)d_ws + xb_b);
    bf16* wsA = (bf16*)((char*)d_ws + xb_b + h_b);
    bf16* wsB = (bf16*)((char*)d_ws + xb_b + h_b + w_b);

    hipFuncSetAttribute((const void*)k_moe1, hipFuncAttributeMaxDynamicSharedMemorySize, 163840);
    hipFuncSetAttribute((const void*)k_g2,   hipFuncAttributeMaxDynamicSharedMemorySize, 163840);

    k_cvt<<<2048, 256, 0, stream>>>(x,  xb,  (long)TT * DD);
    k_cvt<<<2048, 256, 0, stream>>>(w1, wsA, (long)NE * HH * DD);
    k_cvt<<<2048, 256, 0, stream>>>(w3, wsB, (long)NE * HH * DD);
    k_moe1<<<256, 512, 163840, stream>>>(xb, wsA, wsB, counts, h);
    k_cvt<<<2048, 256, 0, stream>>>(w2, wsA, (long)NE * DD * HH);   // reuse slot A
    k_g2<<<1024, 512, 163840, stream>>>(h, wsA, counts, out);
}